// Round 1
// baseline (1876.557 us; speedup 1.0000x reference)
//
#include <hip/hip_runtime.h>
#include <hip/hip_bf16.h>

#define N_NODES 50000
#define N_EDGES 800000
#define D 128
#define BATCHSIZE 64

// Kernel 1: edge scatter-add: agg[dst] += x[src], 32 lanes per edge, float4 per lane
__global__ void edge_scatter_kernel(const float* __restrict__ x,
                                    const int* __restrict__ edge_index,
                                    float* __restrict__ agg) {
    int tid = blockIdx.x * blockDim.x + threadIdx.x;
    int lane = tid & 31;          // 32 threads per edge
    int e = tid >> 5;
    if (e >= N_EDGES) return;
    int src = edge_index[e];
    int dst = edge_index[N_EDGES + e];
    const float4 v = *(const float4*)(x + (size_t)src * D + lane * 4);
    float* dp = agg + (size_t)dst * D + lane * 4;
    atomicAdd(dp + 0, v.x);
    atomicAdd(dp + 1, v.y);
    atomicAdd(dp + 2, v.z);
    atomicAdd(dp + 3, v.w);
}

// Kernel 2: out = relu((1+eps)*x + agg) in-place over the agg buffer,
// plus fused segment-sum of out rows by batch id into S[64][128] and counts[64].
__global__ void finalize_kernel(const float* __restrict__ x,
                                const float* __restrict__ eps,
                                const int* __restrict__ batch,
                                float* __restrict__ out,     // holds agg on entry
                                float* __restrict__ S,       // [64][128], pre-zeroed
                                float* __restrict__ counts)  // [64], pre-zeroed
{
    int tid = blockIdx.x * blockDim.x + threadIdx.x;
    int lane = tid & 31;
    int node = tid >> 5;
    if (node >= N_NODES) return;
    float scale = 1.0f + eps[0];
    const float4 xv = *(const float4*)(x + (size_t)node * D + lane * 4);
    float4 av = *(float4*)(out + (size_t)node * D + lane * 4);
    float4 o;
    o.x = fmaxf(fmaf(scale, xv.x, av.x), 0.0f);
    o.y = fmaxf(fmaf(scale, xv.y, av.y), 0.0f);
    o.z = fmaxf(fmaf(scale, xv.z, av.z), 0.0f);
    o.w = fmaxf(fmaf(scale, xv.w, av.w), 0.0f);
    *(float4*)(out + (size_t)node * D + lane * 4) = o;
    int b = batch[node];
    float* sp = S + (size_t)b * D + lane * 4;
    atomicAdd(sp + 0, o.x);
    atomicAdd(sp + 1, o.y);
    atomicAdd(sp + 2, o.z);
    atomicAdd(sp + 3, o.w);
    if (lane == 0) atomicAdd(counts + b, 1.0f);
}

// Kernel 3: pooled2[b][j] = sum_k S[b][k] * W[k][j] + counts[b]*b_pred[j]
__global__ void pool_gemm_kernel(const float* __restrict__ S,
                                 const float* __restrict__ counts,
                                 const float* __restrict__ W,
                                 const float* __restrict__ b_pred,
                                 float* __restrict__ pooled2) {
    int b = blockIdx.x;      // 64
    int j = threadIdx.x;     // 128
    float acc = counts[b] * b_pred[j];
    const float* srow = S + (size_t)b * D;
#pragma unroll 8
    for (int k = 0; k < D; ++k) {
        acc = fmaf(srow[k], W[(size_t)k * D + j], acc);
    }
    pooled2[(size_t)b * D + j] = acc;
}

extern "C" void kernel_launch(void* const* d_in, const int* in_sizes, int n_in,
                              void* d_out, int out_size, void* d_ws, size_t ws_size,
                              hipStream_t stream) {
    const float* x      = (const float*)d_in[0];
    const float* eps    = (const float*)d_in[1];
    const float* W_pred = (const float*)d_in[2];
    const float* b_pred = (const float*)d_in[3];
    const int*   eidx   = (const int*)d_in[4];
    const int*   batch  = (const int*)d_in[5];

    float* out     = (float*)d_out;                       // [N_NODES][D]
    float* pooled2 = (float*)d_out + (size_t)N_NODES * D; // [BATCHSIZE][D]

    float* S      = (float*)d_ws;                         // [64][128]
    float* counts = (float*)d_ws + BATCHSIZE * D;         // [64]

    // Zero agg accumulator (lives in d_out's `out` region) and S/counts.
    hipMemsetAsync(out, 0, (size_t)N_NODES * D * sizeof(float), stream);
    hipMemsetAsync(d_ws, 0, (BATCHSIZE * D + BATCHSIZE) * sizeof(float), stream);

    // Edge scatter: 800000 edges * 32 threads
    {
        int threads = 256;
        long long total = (long long)N_EDGES * 32;
        int blocks = (int)((total + threads - 1) / threads);
        edge_scatter_kernel<<<blocks, threads, 0, stream>>>(x, eidx, out);
    }

    // Finalize + fused pooling pre-reduction: 50000 nodes * 32 threads
    {
        int threads = 256;
        long long total = (long long)N_NODES * 32;
        int blocks = (int)((total + threads - 1) / threads);
        finalize_kernel<<<blocks, threads, 0, stream>>>(x, eps, batch, out, S, counts);
    }

    // Tiny GEMM: 64 blocks x 128 threads
    pool_gemm_kernel<<<BATCHSIZE, D, 0, stream>>>(S, counts, W_pred, b_pred, pooled2);
}

// Round 2
// 340.531 us; speedup vs baseline: 5.5107x; 5.5107x over previous
//
#include <hip/hip_runtime.h>
#include <hip/hip_bf16.h>

#define N_NODES 50000
#define N_EDGES 800000
#define D 128
#define BATCHSIZE 64

// ---------------- CSR-gather path ----------------

// Kernel A: histogram of destination degrees
__global__ void hist_kernel(const int* __restrict__ edge_index,
                            int* __restrict__ counts) {
    int e = blockIdx.x * blockDim.x + threadIdx.x;
    if (e >= N_EDGES) return;
    int dst = edge_index[N_EDGES + e];
    atomicAdd(&counts[dst], 1);
}

// Kernel B: single-block exclusive scan of counts -> offsets, cursor
__global__ void scan_kernel(const int* __restrict__ counts,
                            int* __restrict__ offsets,
                            int* __restrict__ cursor) {
    __shared__ int buf[1024];
    int tid = threadIdx.x;
    int running = 0;
    for (int base = 0; base < N_NODES; base += 1024) {
        int i = base + tid;
        int v = (i < N_NODES) ? counts[i] : 0;
        buf[tid] = v;
        __syncthreads();
        int xval = v;
        for (int off = 1; off < 1024; off <<= 1) {
            int y = (tid >= off) ? buf[tid - off] : 0;
            __syncthreads();
            xval += y;
            buf[tid] = xval;
            __syncthreads();
        }
        int excl = xval - v + running;
        if (i < N_NODES) { offsets[i] = excl; cursor[i] = excl; }
        running += buf[1023];
        __syncthreads();
    }
}

// Kernel C: scatter edge srcs into CSR buckets
__global__ void fill_csr_kernel(const int* __restrict__ edge_index,
                                int* __restrict__ cursor,
                                int* __restrict__ csr_src) {
    int e = blockIdx.x * blockDim.x + threadIdx.x;
    if (e >= N_EDGES) return;
    int src = edge_index[e];
    int dst = edge_index[N_EDGES + e];
    int pos = atomicAdd(&cursor[dst], 1);
    csr_src[pos] = src;
}

// Kernel D: gather-aggregate + fused finalize: out = relu((1+eps)x + agg)
// 32 lanes per node, float4 per lane.
__global__ void gather_finalize_kernel(const float* __restrict__ x,
                                       const float* __restrict__ eps,
                                       const int* __restrict__ offsets,
                                       const int* __restrict__ counts,
                                       const int* __restrict__ csr_src,
                                       float* __restrict__ out) {
    int tid = blockIdx.x * blockDim.x + threadIdx.x;
    int lane = tid & 31;
    int node = tid >> 5;
    if (node >= N_NODES) return;
    int start = offsets[node];
    int deg = counts[node];
    float4 acc = make_float4(0.f, 0.f, 0.f, 0.f);
    int k = 0;
    for (; k + 2 <= deg; k += 2) {
        int s0 = csr_src[start + k];
        int s1 = csr_src[start + k + 1];
        const float4 v0 = *(const float4*)(x + (size_t)s0 * D + lane * 4);
        const float4 v1 = *(const float4*)(x + (size_t)s1 * D + lane * 4);
        acc.x += v0.x + v1.x;
        acc.y += v0.y + v1.y;
        acc.z += v0.z + v1.z;
        acc.w += v0.w + v1.w;
    }
    for (; k < deg; ++k) {
        int s0 = csr_src[start + k];
        const float4 v0 = *(const float4*)(x + (size_t)s0 * D + lane * 4);
        acc.x += v0.x; acc.y += v0.y; acc.z += v0.z; acc.w += v0.w;
    }
    float scale = 1.0f + eps[0];
    const float4 xv = *(const float4*)(x + (size_t)node * D + lane * 4);
    float4 o;
    o.x = fmaxf(fmaf(scale, xv.x, acc.x), 0.0f);
    o.y = fmaxf(fmaf(scale, xv.y, acc.y), 0.0f);
    o.z = fmaxf(fmaf(scale, xv.z, acc.z), 0.0f);
    o.w = fmaxf(fmaf(scale, xv.w, acc.w), 0.0f);
    *(float4*)(out + (size_t)node * D + lane * 4) = o;
}

__device__ inline int lower_bound_dev(const int* __restrict__ a, int n, int key) {
    int lo = 0, hi = n;
    while (lo < hi) {
        int mid = (lo + hi) >> 1;
        if (a[mid] < key) lo = mid + 1; else hi = mid;
    }
    return lo;
}

// Kernel E: per-batch segment sum of out rows, 8 slices per batch, combine via atomics.
__global__ void pool_partial_kernel(const float* __restrict__ out,
                                    const int* __restrict__ batch,
                                    float* __restrict__ S) {
    int b = blockIdx.x >> 3;
    int s = blockIdx.x & 7;
    int j = threadIdx.x;  // 128
    int lo = lower_bound_dev(batch, N_NODES, b);
    int hi = lower_bound_dev(batch, N_NODES, b + 1);
    int len = hi - lo;
    int per = (len + 7) >> 3;
    int nlo = lo + s * per;
    int nhi = nlo + per; if (nhi > hi) nhi = hi;
    float acc = 0.0f;
    for (int n = nlo; n < nhi; ++n) {
        acc += out[(size_t)n * D + j];
    }
    if (acc != 0.0f || true) atomicAdd(&S[(size_t)b * D + j], acc);
}

// Kernel F: pooled2[b][j] = sum_k S[b][k]*W[k][j] + count(b)*b_pred[j]
__global__ void pool_gemm_kernel(const float* __restrict__ S,
                                 const int* __restrict__ batch,
                                 const float* __restrict__ W,
                                 const float* __restrict__ b_pred,
                                 float* __restrict__ pooled2) {
    int b = blockIdx.x;      // 64
    int j = threadIdx.x;     // 128
    int lo = lower_bound_dev(batch, N_NODES, b);
    int hi = lower_bound_dev(batch, N_NODES, b + 1);
    float acc = (float)(hi - lo) * b_pred[j];
    const float* srow = S + (size_t)b * D;
#pragma unroll 8
    for (int k = 0; k < D; ++k) {
        acc = fmaf(srow[k], W[(size_t)k * D + j], acc);
    }
    pooled2[(size_t)b * D + j] = acc;
}

// ---------------- fallback (round-1) path ----------------

__global__ void edge_scatter_kernel(const float* __restrict__ x,
                                    const int* __restrict__ edge_index,
                                    float* __restrict__ agg) {
    int tid = blockIdx.x * blockDim.x + threadIdx.x;
    int lane = tid & 31;
    int e = tid >> 5;
    if (e >= N_EDGES) return;
    int src = edge_index[e];
    int dst = edge_index[N_EDGES + e];
    const float4 v = *(const float4*)(x + (size_t)src * D + lane * 4);
    float* dp = agg + (size_t)dst * D + lane * 4;
    atomicAdd(dp + 0, v.x);
    atomicAdd(dp + 1, v.y);
    atomicAdd(dp + 2, v.z);
    atomicAdd(dp + 3, v.w);
}

__global__ void finalize_kernel(const float* __restrict__ x,
                                const float* __restrict__ eps,
                                const int* __restrict__ batch,
                                float* __restrict__ out,
                                float* __restrict__ S,
                                float* __restrict__ counts) {
    int tid = blockIdx.x * blockDim.x + threadIdx.x;
    int lane = tid & 31;
    int node = tid >> 5;
    if (node >= N_NODES) return;
    float scale = 1.0f + eps[0];
    const float4 xv = *(const float4*)(x + (size_t)node * D + lane * 4);
    float4 av = *(float4*)(out + (size_t)node * D + lane * 4);
    float4 o;
    o.x = fmaxf(fmaf(scale, xv.x, av.x), 0.0f);
    o.y = fmaxf(fmaf(scale, xv.y, av.y), 0.0f);
    o.z = fmaxf(fmaf(scale, xv.z, av.z), 0.0f);
    o.w = fmaxf(fmaf(scale, xv.w, av.w), 0.0f);
    *(float4*)(out + (size_t)node * D + lane * 4) = o;
    int b = batch[node];
    float* sp = S + (size_t)b * D + lane * 4;
    atomicAdd(sp + 0, o.x);
    atomicAdd(sp + 1, o.y);
    atomicAdd(sp + 2, o.z);
    atomicAdd(sp + 3, o.w);
    if (lane == 0) atomicAdd(counts + b, 1.0f);
}

__global__ void pool_gemm_fallback_kernel(const float* __restrict__ S,
                                          const float* __restrict__ counts,
                                          const float* __restrict__ W,
                                          const float* __restrict__ b_pred,
                                          float* __restrict__ pooled2) {
    int b = blockIdx.x;
    int j = threadIdx.x;
    float acc = counts[b] * b_pred[j];
    const float* srow = S + (size_t)b * D;
#pragma unroll 8
    for (int k = 0; k < D; ++k) {
        acc = fmaf(srow[k], W[(size_t)k * D + j], acc);
    }
    pooled2[(size_t)b * D + j] = acc;
}

extern "C" void kernel_launch(void* const* d_in, const int* in_sizes, int n_in,
                              void* d_out, int out_size, void* d_ws, size_t ws_size,
                              hipStream_t stream) {
    const float* x      = (const float*)d_in[0];
    const float* eps    = (const float*)d_in[1];
    const float* W_pred = (const float*)d_in[2];
    const float* b_pred = (const float*)d_in[3];
    const int*   eidx   = (const int*)d_in[4];
    const int*   batch  = (const int*)d_in[5];

    float* out     = (float*)d_out;                       // [N_NODES][D]
    float* pooled2 = (float*)d_out + (size_t)N_NODES * D; // [BATCHSIZE][D]

    // ws layout (4B units): counts[50000] | S[8192] | offsets[50000] | cursor[50000] | csr_src[800000]
    const size_t need = (size_t)(50000 + 8192 + 50000 + 50000 + 800000) * 4;

    if (ws_size >= need) {
        int*   counts  = (int*)d_ws;
        float* S       = (float*)d_ws + 50000;
        int*   offsets = (int*)d_ws + 58192;
        int*   cursor  = (int*)d_ws + 108192;
        int*   csr_src = (int*)d_ws + 158192;

        // zero counts + S in one shot (contiguous)
        hipMemsetAsync(d_ws, 0, (size_t)(50000 + 8192) * 4, stream);

        hist_kernel<<<(N_EDGES + 255) / 256, 256, 0, stream>>>(eidx, counts);
        scan_kernel<<<1, 1024, 0, stream>>>(counts, offsets, cursor);
        fill_csr_kernel<<<(N_EDGES + 255) / 256, 256, 0, stream>>>(eidx, cursor, csr_src);
        {
            long long total = (long long)N_NODES * 32;
            int blocks = (int)((total + 255) / 256);
            gather_finalize_kernel<<<blocks, 256, 0, stream>>>(x, eps, offsets, counts, csr_src, out);
        }
        pool_partial_kernel<<<BATCHSIZE * 8, D, 0, stream>>>(out, batch, S);
        pool_gemm_kernel<<<BATCHSIZE, D, 0, stream>>>(S, batch, W_pred, b_pred, pooled2);
    } else {
        // fallback: atomic scatter path (round 1)
        float* S      = (float*)d_ws;
        float* countsf = (float*)d_ws + BATCHSIZE * D;
        hipMemsetAsync(out, 0, (size_t)N_NODES * D * sizeof(float), stream);
        hipMemsetAsync(d_ws, 0, (BATCHSIZE * D + BATCHSIZE) * sizeof(float), stream);
        {
            long long total = (long long)N_EDGES * 32;
            int blocks = (int)((total + 255) / 256);
            edge_scatter_kernel<<<blocks, 256, 0, stream>>>(x, eidx, out);
        }
        {
            long long total = (long long)N_NODES * 32;
            int blocks = (int)((total + 255) / 256);
            finalize_kernel<<<blocks, 256, 0, stream>>>(x, eps, batch, out, S, countsf);
        }
        pool_gemm_fallback_kernel<<<BATCHSIZE, D, 0, stream>>>(S, countsf, W_pred, b_pred, pooled2);
    }
}

// Round 3
// 287.672 us; speedup vs baseline: 6.5233x; 1.1837x over previous
//
#include <hip/hip_runtime.h>
#include <hip/hip_bf16.h>

#define N_NODES 50000
#define N_EDGES 800000
#define D 128
#define BATCHSIZE 64

// ---------------- CSR-gather path ----------------

// Kernel A: histogram of destination degrees (int4-vectorized, 4 edges/thread)
__global__ void hist_kernel(const int* __restrict__ edge_index,
                            int* __restrict__ counts) {
    int t = blockIdx.x * blockDim.x + threadIdx.x;
    int e = t * 4;
    if (e >= N_EDGES) return;
    int4 d = *(const int4*)(edge_index + N_EDGES + e);
    atomicAdd(&counts[d.x], 1);
    atomicAdd(&counts[d.y], 1);
    atomicAdd(&counts[d.z], 1);
    atomicAdd(&counts[d.w], 1);
}

// Kernel B: single-block exclusive scan, wave-shuffle based.
// 1024 threads x 4 elements = 4096/chunk, 13 chunks, ~4 barriers/chunk.
__global__ void scan_kernel(const int* __restrict__ counts,
                            int* __restrict__ offsets,
                            int* __restrict__ cursor) {
    __shared__ int waveSums[16];
    __shared__ int waveOff[17];
    __shared__ int s_running;
    int tid = threadIdx.x;
    int lane = tid & 63;
    int wid = tid >> 6;
    if (tid == 0) s_running = 0;
    __syncthreads();
    const int CHUNK = 4096;
    for (int base = 0; base < N_NODES; base += CHUNK) {
        int i0 = base + tid * 4;
        int v0 = 0, v1 = 0, v2 = 0, v3 = 0;
        if (i0 < N_NODES) {  // N_NODES % 4 == 0 -> whole group in-bounds
            int4 c = *(const int4*)(counts + i0);
            v0 = c.x; v1 = c.y; v2 = c.z; v3 = c.w;
        }
        int s1 = v0 + v1, s2 = s1 + v2, s3 = s2 + v3;
        // wave inclusive scan of per-thread totals
        int w = s3;
#pragma unroll
        for (int off = 1; off < 64; off <<= 1) {
            int y = __shfl_up(w, off, 64);
            if (lane >= off) w += y;
        }
        if (lane == 63) waveSums[wid] = w;
        __syncthreads();
        if (tid == 0) {
            int acc = 0;
#pragma unroll
            for (int k = 0; k < 16; ++k) { waveOff[k] = acc; acc += waveSums[k]; }
            waveOff[16] = acc;
        }
        __syncthreads();
        int running = s_running;
        int b = running + waveOff[wid] + (w - s3);
        if (i0 < N_NODES) {
            offsets[i0 + 0] = b;      cursor[i0 + 0] = b;
            offsets[i0 + 1] = b + v0; cursor[i0 + 1] = b + v0;
            offsets[i0 + 2] = b + s1; cursor[i0 + 2] = b + s1;
            offsets[i0 + 3] = b + s2; cursor[i0 + 3] = b + s2;
        }
        __syncthreads();
        if (tid == 0) s_running = running + waveOff[16];
        __syncthreads();
    }
}

// Kernel C: scatter edge srcs into CSR buckets (int4-vectorized)
__global__ void fill_csr_kernel(const int* __restrict__ edge_index,
                                int* __restrict__ cursor,
                                int* __restrict__ csr_src) {
    int t = blockIdx.x * blockDim.x + threadIdx.x;
    int e = t * 4;
    if (e >= N_EDGES) return;
    int4 s = *(const int4*)(edge_index + e);
    int4 d = *(const int4*)(edge_index + N_EDGES + e);
    int p0 = atomicAdd(&cursor[d.x], 1); csr_src[p0] = s.x;
    int p1 = atomicAdd(&cursor[d.y], 1); csr_src[p1] = s.y;
    int p2 = atomicAdd(&cursor[d.z], 1); csr_src[p2] = s.z;
    int p3 = atomicAdd(&cursor[d.w], 1); csr_src[p3] = s.w;
}

// Kernel D: gather-aggregate + fused finalize: out = relu((1+eps)x + agg)
// 32 lanes per node, float4 per lane; 4-way unrolled neighbor loop for MLP.
__global__ void gather_finalize_kernel(const float* __restrict__ x,
                                       const float* __restrict__ eps,
                                       const int* __restrict__ offsets,
                                       const int* __restrict__ counts,
                                       const int* __restrict__ csr_src,
                                       float* __restrict__ out) {
    int tid = blockIdx.x * blockDim.x + threadIdx.x;
    int lane = tid & 31;
    int node = tid >> 5;
    if (node >= N_NODES) return;
    int start = offsets[node];
    int deg = counts[node];
    float4 acc = make_float4(0.f, 0.f, 0.f, 0.f);
    int k = 0;
    for (; k + 4 <= deg; k += 4) {
        int s0 = csr_src[start + k];
        int s1 = csr_src[start + k + 1];
        int s2 = csr_src[start + k + 2];
        int s3 = csr_src[start + k + 3];
        const float4 v0 = *(const float4*)(x + (size_t)s0 * D + lane * 4);
        const float4 v1 = *(const float4*)(x + (size_t)s1 * D + lane * 4);
        const float4 v2 = *(const float4*)(x + (size_t)s2 * D + lane * 4);
        const float4 v3 = *(const float4*)(x + (size_t)s3 * D + lane * 4);
        acc.x += (v0.x + v1.x) + (v2.x + v3.x);
        acc.y += (v0.y + v1.y) + (v2.y + v3.y);
        acc.z += (v0.z + v1.z) + (v2.z + v3.z);
        acc.w += (v0.w + v1.w) + (v2.w + v3.w);
    }
    for (; k < deg; ++k) {
        int s0 = csr_src[start + k];
        const float4 v0 = *(const float4*)(x + (size_t)s0 * D + lane * 4);
        acc.x += v0.x; acc.y += v0.y; acc.z += v0.z; acc.w += v0.w;
    }
    float scale = 1.0f + eps[0];
    const float4 xv = *(const float4*)(x + (size_t)node * D + lane * 4);
    float4 o;
    o.x = fmaxf(fmaf(scale, xv.x, acc.x), 0.0f);
    o.y = fmaxf(fmaf(scale, xv.y, acc.y), 0.0f);
    o.z = fmaxf(fmaf(scale, xv.z, acc.z), 0.0f);
    o.w = fmaxf(fmaf(scale, xv.w, acc.w), 0.0f);
    *(float4*)(out + (size_t)node * D + lane * 4) = o;
}

__device__ inline int lower_bound_dev(const int* __restrict__ a, int n, int key) {
    int lo = 0, hi = n;
    while (lo < hi) {
        int mid = (lo + hi) >> 1;
        if (a[mid] < key) lo = mid + 1; else hi = mid;
    }
    return lo;
}

// Kernel E: per-batch segment sum of out rows, 8 slices per batch, combine via atomics.
__global__ void pool_partial_kernel(const float* __restrict__ out,
                                    const int* __restrict__ batch,
                                    float* __restrict__ S) {
    int b = blockIdx.x >> 3;
    int s = blockIdx.x & 7;
    int j = threadIdx.x;  // 128
    int lo = lower_bound_dev(batch, N_NODES, b);
    int hi = lower_bound_dev(batch, N_NODES, b + 1);
    int len = hi - lo;
    int per = (len + 7) >> 3;
    int nlo = lo + s * per;
    int nhi = nlo + per; if (nhi > hi) nhi = hi;
    float acc = 0.0f;
    for (int n = nlo; n < nhi; ++n) {
        acc += out[(size_t)n * D + j];
    }
    atomicAdd(&S[(size_t)b * D + j], acc);
}

// Kernel F: pooled2[b][j] = sum_k S[b][k]*W[k][j] + count(b)*b_pred[j]
__global__ void pool_gemm_kernel(const float* __restrict__ S,
                                 const int* __restrict__ batch,
                                 const float* __restrict__ W,
                                 const float* __restrict__ b_pred,
                                 float* __restrict__ pooled2) {
    int b = blockIdx.x;      // 64
    int j = threadIdx.x;     // 128
    int lo = lower_bound_dev(batch, N_NODES, b);
    int hi = lower_bound_dev(batch, N_NODES, b + 1);
    float acc = (float)(hi - lo) * b_pred[j];
    const float* srow = S + (size_t)b * D;
#pragma unroll 8
    for (int k = 0; k < D; ++k) {
        acc = fmaf(srow[k], W[(size_t)k * D + j], acc);
    }
    pooled2[(size_t)b * D + j] = acc;
}

// ---------------- fallback (round-1) path ----------------

__global__ void edge_scatter_kernel(const float* __restrict__ x,
                                    const int* __restrict__ edge_index,
                                    float* __restrict__ agg) {
    int tid = blockIdx.x * blockDim.x + threadIdx.x;
    int lane = tid & 31;
    int e = tid >> 5;
    if (e >= N_EDGES) return;
    int src = edge_index[e];
    int dst = edge_index[N_EDGES + e];
    const float4 v = *(const float4*)(x + (size_t)src * D + lane * 4);
    float* dp = agg + (size_t)dst * D + lane * 4;
    atomicAdd(dp + 0, v.x);
    atomicAdd(dp + 1, v.y);
    atomicAdd(dp + 2, v.z);
    atomicAdd(dp + 3, v.w);
}

__global__ void finalize_kernel(const float* __restrict__ x,
                                const float* __restrict__ eps,
                                const int* __restrict__ batch,
                                float* __restrict__ out,
                                float* __restrict__ S,
                                float* __restrict__ counts) {
    int tid = blockIdx.x * blockDim.x + threadIdx.x;
    int lane = tid & 31;
    int node = tid >> 5;
    if (node >= N_NODES) return;
    float scale = 1.0f + eps[0];
    const float4 xv = *(const float4*)(x + (size_t)node * D + lane * 4);
    float4 av = *(float4*)(out + (size_t)node * D + lane * 4);
    float4 o;
    o.x = fmaxf(fmaf(scale, xv.x, av.x), 0.0f);
    o.y = fmaxf(fmaf(scale, xv.y, av.y), 0.0f);
    o.z = fmaxf(fmaf(scale, xv.z, av.z), 0.0f);
    o.w = fmaxf(fmaf(scale, xv.w, av.w), 0.0f);
    *(float4*)(out + (size_t)node * D + lane * 4) = o;
    int b = batch[node];
    float* sp = S + (size_t)b * D + lane * 4;
    atomicAdd(sp + 0, o.x);
    atomicAdd(sp + 1, o.y);
    atomicAdd(sp + 2, o.z);
    atomicAdd(sp + 3, o.w);
    if (lane == 0) atomicAdd(counts + b, 1.0f);
}

__global__ void pool_gemm_fallback_kernel(const float* __restrict__ S,
                                          const float* __restrict__ counts,
                                          const float* __restrict__ W,
                                          const float* __restrict__ b_pred,
                                          float* __restrict__ pooled2) {
    int b = blockIdx.x;
    int j = threadIdx.x;
    float acc = counts[b] * b_pred[j];
    const float* srow = S + (size_t)b * D;
#pragma unroll 8
    for (int k = 0; k < D; ++k) {
        acc = fmaf(srow[k], W[(size_t)k * D + j], acc);
    }
    pooled2[(size_t)b * D + j] = acc;
}

extern "C" void kernel_launch(void* const* d_in, const int* in_sizes, int n_in,
                              void* d_out, int out_size, void* d_ws, size_t ws_size,
                              hipStream_t stream) {
    const float* x      = (const float*)d_in[0];
    const float* eps    = (const float*)d_in[1];
    const float* W_pred = (const float*)d_in[2];
    const float* b_pred = (const float*)d_in[3];
    const int*   eidx   = (const int*)d_in[4];
    const int*   batch  = (const int*)d_in[5];

    float* out     = (float*)d_out;                       // [N_NODES][D]
    float* pooled2 = (float*)d_out + (size_t)N_NODES * D; // [BATCHSIZE][D]

    // ws layout (4B units): counts[50000] | S[8192] | offsets[50000] | cursor[50000] | csr_src[800000]
    const size_t need = (size_t)(50000 + 8192 + 50000 + 50000 + 800000) * 4;

    if (ws_size >= need) {
        int*   counts  = (int*)d_ws;
        float* S       = (float*)d_ws + 50000;
        int*   offsets = (int*)d_ws + 58192;
        int*   cursor  = (int*)d_ws + 108192;
        int*   csr_src = (int*)d_ws + 158192;

        // zero counts + S in one shot (contiguous)
        hipMemsetAsync(d_ws, 0, (size_t)(50000 + 8192) * 4, stream);

        hist_kernel<<<(N_EDGES / 4 + 255) / 256, 256, 0, stream>>>(eidx, counts);
        scan_kernel<<<1, 1024, 0, stream>>>(counts, offsets, cursor);
        fill_csr_kernel<<<(N_EDGES / 4 + 255) / 256, 256, 0, stream>>>(eidx, cursor, csr_src);
        {
            long long total = (long long)N_NODES * 32;
            int blocks = (int)((total + 255) / 256);
            gather_finalize_kernel<<<blocks, 256, 0, stream>>>(x, eps, offsets, counts, csr_src, out);
        }
        pool_partial_kernel<<<BATCHSIZE * 8, D, 0, stream>>>(out, batch, S);
        pool_gemm_kernel<<<BATCHSIZE, D, 0, stream>>>(S, batch, W_pred, b_pred, pooled2);
    } else {
        // fallback: atomic scatter path (round 1)
        float* S      = (float*)d_ws;
        float* countsf = (float*)d_ws + BATCHSIZE * D;
        hipMemsetAsync(out, 0, (size_t)N_NODES * D * sizeof(float), stream);
        hipMemsetAsync(d_ws, 0, (BATCHSIZE * D + BATCHSIZE) * sizeof(float), stream);
        {
            long long total = (long long)N_EDGES * 32;
            int blocks = (int)((total + 255) / 256);
            edge_scatter_kernel<<<blocks, 256, 0, stream>>>(x, eidx, out);
        }
        {
            long long total = (long long)N_NODES * 32;
            int blocks = (int)((total + 255) / 256);
            finalize_kernel<<<blocks, 256, 0, stream>>>(x, eps, batch, out, S, countsf);
        }
        pool_gemm_fallback_kernel<<<BATCHSIZE, D, 0, stream>>>(S, countsf, W_pred, b_pred, pooled2);
    }
}